// Round 14
// baseline (90.687 us; speedup 1.0000x reference)
//
#include <hip/hip_runtime.h>

// Problem constants (fixed by setup_inputs)
constexpr int Bn = 128, Cn = 3, Sn = 256;
constexpr int HWn = Sn * Sn;          // 65536
constexpr int NPLANE = Bn * Cn;       // 384
constexpr float DTf = 0.05f;
constexpr float EPSf = 1e-6f;
constexpr float MAXCf = 1.0f;

// ws float layout:
//   [128..10111]    tapx [3 c][13 d][256 i]
//   [10368..20351]  tapy [3 c][13 d][256 i]  (dg^3 folded in)
#define WS_TAPX 128
#define WS_TAPY 10368

// ---- build composed banded operator taps (+ fused spatial mean) ----------
// All T_k = I + r_k*L commute; composed X (resp Y) = product of the three
// x-dir (y-dir) tridiagonal inverses. Thread j applies the three EXACT
// reference Thomas solves (incl. b0+eps, denom clamp, x_n = dp_n) to basis
// vector e_j, keeping rows [j-16, j+16] in registers. Band +-6 tail ~3e-10.
__global__ void build_taps(const float* __restrict__ alpha_base,
                           const float* __restrict__ beta_base,
                           const float* __restrict__ aspat,
                           const float* __restrict__ bspat,
                           const float* __restrict__ coupling,
                           float* __restrict__ ws) {
  __shared__ double sm[256];
  __shared__ float cp3[3][288], di3[3][288];   // padded: idx = i+16, zeros outside [0,255]
  __shared__ float s_mean;
  const int dirc = blockIdx.x, dir = dirc / 3, c = dirc % 3;
  const int j = threadIdx.x;
  {
    const float4* p = (const float4*)((dir == 0 ? aspat : bspat) + c * HWn) + j;
    double acc = 0.0;
#pragma unroll
    for (int k2 = 0; k2 < 64; ++k2) {
      float4 v = p[k2 * 256];
      acc += (double)v.x + (double)v.y + (double)v.z + (double)v.w;
    }
    sm[j] = acc;
    __syncthreads();
    for (int s2 = 128; s2 > 0; s2 >>= 1) {
      if (j < s2) sm[j] += sm[j + s2];
      __syncthreads();
    }
    if (j == 0) s_mean = (float)(sm[0] * (1.0 / 65536.0));
    __syncthreads();
  }
  if (j < 3) {
    const int k = j;
    const float base = (dir == 0) ? alpha_base[c] : beta_base[c];
    const float coef = fminf(fmaxf(base + s_mean * ((float)k * DTf), EPSf), MAXCf);
    const float r = coef * (DTf * 0.5f);       // DX = 1
    for (int p = 0; p < 16; ++p) {
      cp3[k][p] = 0.f; di3[k][p] = 0.f;
      cp3[k][272 + p] = 0.f; di3[k][272 + p] = 0.f;
    }
    float b0 = 1.f + r + EPSf;                 // reference: b[0] + eps
    float cq = -r / b0, dq = 1.f / b0;
    cp3[k][16] = cq; di3[k][16] = dq;
    for (int i = 1; i < 256; ++i) {
      float b = (i == 255) ? (1.f + r) : (1.f + 2.f * r);
      float den = fmaxf(b + r * cq, EPSf);     // b - a*cp_prev, a = -r
      cq = -r / den; dq = 1.f / den;
      cp3[k][16 + i] = cq; di3[k][16 + i] = dq;
    }
  }
  float* tb = ws + ((dir == 0) ? WS_TAPX : WS_TAPY) + c * 13 * 256;
#pragma unroll
  for (int d = 0; d < 13; ++d) tb[d * 256 + j] = 0.f;   // OOB-source taps stay 0
  __syncthreads();

  float z[33];                                  // o = 0..32 <-> row i = j-16+o
#pragma unroll
  for (int o = 0; o < 33; ++o) z[o] = (o == 16) ? 1.f : 0.f;
#pragma unroll
  for (int k = 0; k < 3; ++k) {
    float dp = 0.f;
#pragma unroll
    for (int o = 0; o < 33; ++o) {              // forward: dp in place
      const int p = j + o;
      dp = fmaf(-cp3[k][p], dp, z[o] * di3[k][p]);
      z[o] = dp;
    }
    float x = 0.f;
#pragma unroll
    for (int o = 32; o >= 0; --o) {             // backward: x = dp - cp*x_next
      const int p = j + o;
      x = fmaf(-cp3[k][p], x, z[o]);
      z[o] = x;
    }
  }
  float scale = 1.f;
  if (dir == 1) {
    float dgc = coupling[c * 3 + c];
    scale = dgc * dgc * dgc;                    // diag applied after each step
  }
#pragma unroll
  for (int o = -6; o <= 6; ++o) {
    const int i = j + o;                        // output row; d = 6 - o
    if ((unsigned)i < 256u) tb[(6 - o) * 256 + i] = z[o + 16] * scale;
  }
}

// ---- hot kernel: out = Y * u * X^T, separable 13-tap stencil -------------
// (512,4): VGPR <= 64 -> 2 blocks/CU (R8/R11/R13-proven envelope).
// LDS layout: element (rl, col) at word rl*256 + 4*skew(colq) + (col&3),
// skew(q) = q ^ (q>>3) — an INVOLUTION that spreads a row's quads {4s+c}
// over all 8 bank-group positions (R13's layout had only 2 -> 8-way conflict).
// DMA: lane l's slot l receives source quad skew(l) (both-sides involution).
// Stage 1 (x-conv, barrier-free): wave wv owns rows {4wv+j+32m} — it DMAs
// them, per-wave vmcnt(0), reads 8 quads/unit from LDS, conv (interior taps
// SGPR; cols 0-5/250-255 recomputed with true per-col taps — zero taps kill
// clamped-garbage inputs), writes in place (wave-lockstep: all reads precede
// writes in program order; all halo quads of a row live in the same wave).
// Stage 2 (y-conv): col-pair units, rolling float2 win[13]; taps via
// wave-uniform s_load; coalesced float2 stores. ONE barrier total.
__global__ __launch_bounds__(512, 4) void conv3(
    const float* __restrict__ src, float* __restrict__ dst,
    const float* __restrict__ ws) {
  __shared__ float vt[76 * 256];               // 77824 B
  const int t = threadIdx.x;
  // XCD-bijective swizzle: 1536 = 8*192
  const int logical = (blockIdx.x & 7) * 192 + (blockIdx.x >> 3);
  const int plane = logical >> 2;
  const int st = logical & 3;
  const int c = plane % 3;
  const int h0 = st * 64;
  const int a = (st == 0) ? 0 : (h0 - 6);
  const int b = (st == 3) ? 256 : (h0 + 70);
  const int Wv = b - a;                        // 70 or 76
  const float* tpx = ws + WS_TAPX + c * 3328;
  const float* tpy = ws + WS_TAPY + c * 3328;
  const float* srcp = src + (size_t)plane * HWn;

  // ---- DMA: wave wv loads its own rows 4wv+jj+32m (pre-skewed source) ----
  {
    const int wv = t >> 6, l = t & 63;
    const int fl = l ^ (l >> 3);               // involution: source quad for slot l
#pragma unroll
    for (int m = 0; m < 3; ++m) {
#pragma unroll
      for (int jj = 0; jj < 4; ++jj) {
        const int rl = 4 * wv + jj + 32 * m;
        if (rl < Wv) {
          const float* gp = srcp + (size_t)(a + rl) * 256 + (fl << 2);
          __builtin_amdgcn_global_load_lds(
              (const __attribute__((address_space(1))) void*)gp,
              (__attribute__((address_space(3))) void*)(vt + rl * 256), 16, 0, 0);
        }
      }
    }
  }
  float tx[13];                                 // interior x-taps (uniform -> s_load)
#pragma unroll
  for (int d = 0; d < 13; ++d) tx[d] = tpx[d * 256 + 128];
  asm volatile("s_waitcnt vmcnt(0)" ::: "memory");   // own rows only (per-wave)
  __builtin_amdgcn_sched_barrier(0);

  // ---- stage 1: x-conv in place. unit = (row rl, 16-col seg s) ----
  const int NU = 16 * Wv;
#pragma unroll
  for (int p = 0; p < 3; ++p) {
    const int u = t + 512 * p;
    if (u < NU) {
      const int s = u & 15, rl = u >> 4;
      float* base = vt + rl * 256;
      float in_[32];                            // cols [16s-8, 16s+24)
#pragma unroll
      for (int mq = 0; mq < 8; ++mq) {
        int g = 4 * s - 2 + mq;
        g = g < 0 ? 0 : (g > 63 ? 63 : g);      // clamped value x zero tap
        const int sl = g ^ (g >> 3);
        *(float4*)&in_[4 * mq] = *(const float4*)(base + 4 * sl);
      }
      float acc[16];
#pragma unroll
      for (int e = 0; e < 16; ++e) acc[e] = tx[0] * in_[e + 2];
#pragma unroll
      for (int d = 1; d < 13; ++d)
#pragma unroll
        for (int e = 0; e < 16; ++e) acc[e] = fmaf(tx[d], in_[e + 2 + d], acc[e]);
      if (s == 0) {                             // fix cols 0..5 (true taps)
#pragma unroll
        for (int e = 0; e < 6; ++e) {
          float ac = 0.f;
#pragma unroll
          for (int d = 0; d < 13; ++d) ac = fmaf(tpx[d * 256 + e], in_[e + 2 + d], ac);
          acc[e] = ac;
        }
      } else if (s == 15) {                     // fix cols 250..255
#pragma unroll
        for (int e = 10; e < 16; ++e) {
          float ac = 0.f;
#pragma unroll
          for (int d = 0; d < 13; ++d) ac = fmaf(tpx[d * 256 + 240 + e], in_[e + 2 + d], ac);
          acc[e] = ac;
        }
      }
#pragma unroll
      for (int jj = 0; jj < 4; ++jj) {          // in-place write (own quads)
        const int q = 4 * s + jj;
        const int sl = q ^ (q >> 3);
        *(float4*)(base + 4 * sl) =
            make_float4(acc[4 * jj], acc[4 * jj + 1], acc[4 * jj + 2], acc[4 * jj + 3]);
      }
    }
  }
  __syncthreads();                              // the ONE barrier

  // ---- stage 2: y-conv. unit = (col-pair pr, 16-row chunk rc) ----
  const int pr = t & 127, rc = t >> 7;
  const int jq = pr >> 1;
  const int wpos = ((jq ^ (jq >> 3)) << 2) | ((pr & 1) * 2);
  const int g0 = h0 + 16 * rc;
  float2 win[13];                               // rows g-6 .. g+6, one col-pair
#pragma unroll
  for (int m = 0; m < 12; ++m) {
    int gg = g0 - 6 + m;
    gg = gg < a ? a : gg;                       // clamped read x zero tap
    win[m] = *(const float2*)(vt + (gg - a) * 256 + wpos);
  }
  float* dstp = dst + (size_t)plane * HWn + 2 * pr;
#pragma unroll
  for (int rr = 0; rr < 16; ++rr) {
    const int g = g0 + rr;
    {
      int gg = g + 6;
      gg = gg > b - 1 ? b - 1 : gg;
      win[12] = *(const float2*)(vt + (gg - a) * 256 + wpos);
    }
    const int gu = __builtin_amdgcn_readfirstlane(g);
    float ox, oy;
    {
      const float ty = tpy[gu];                 // wave-uniform -> s_load
      ox = ty * win[0].x; oy = ty * win[0].y;
    }
#pragma unroll
    for (int d = 1; d < 13; ++d) {
      const float ty = tpy[d * 256 + gu];
      ox = fmaf(ty, win[d].x, ox);
      oy = fmaf(ty, win[d].y, oy);
    }
    *(float2*)(dstp + (size_t)g * 256) = make_float2(ox, oy);
#pragma unroll
    for (int m = 0; m < 12; ++m) win[m] = win[m + 1];
  }
}

extern "C" void kernel_launch(void* const* d_in, const int* in_sizes, int n_in,
                              void* d_out, int out_size, void* d_ws, size_t ws_size,
                              hipStream_t stream) {
  const float* u = (const float*)d_in[0];
  const float* alpha_base = (const float*)d_in[1];
  const float* beta_base = (const float*)d_in[2];
  const float* alpha_spatial = (const float*)d_in[3];
  const float* beta_spatial = (const float*)d_in[4];
  const float* coupling = (const float*)d_in[5];
  float* out = (float*)d_out;
  float* ws = (float*)d_ws;

  build_taps<<<6, 256, 0, stream>>>(alpha_base, beta_base,
                                    alpha_spatial, beta_spatial, coupling, ws);
  conv3<<<NPLANE * 4, 512, 0, stream>>>(u, out, ws);
}